// Round 18
// baseline (9522.920 us; speedup 1.0000x reference)
//
#include <hip/hip_runtime.h>
#include <math.h>

#define NB   16      // blocks
#define NTH  256     // threads per block
#define CH   128     // neurons per block (N/NB)
#define NN   2048    // N
#define DD   64      // D
#define TT   512     // T
#define KWTA 256
#define PA   65      // pad for [CH][64+1] rows (Dx, Dy)
#define PB   132     // pad for [64][128+4] rows (rho), comb access 2-way-free

typedef float f32x4 __attribute__((ext_vector_type(4)));

// ---- cross-block communication (single-buffered; WAR-safe by barrier deps) --
struct __align__(128) BarFlag { unsigned v; unsigned pad[31]; };
__device__ BarFlag g_flag[NB];
__device__ __align__(16) float    g_rfT[DD][16];  // rho@x_un partials, [d][block]
__device__ __align__(16) double   g_L1w[64];      // per-WAVE L1 partials (b*4+wv)
__device__ __align__(16) float    g_xg[NN];       // UNNORMALIZED xtun (at A)
__device__ __align__(16) float    g_yg[NN];
__device__ __align__(16) unsigned g_yh[NB][256];  // per-block y L0 histograms
__device__ __align__(16) unsigned g_xh[NB][256];  // per-block x L0 histograms
__device__ __align__(16) float    g_ET[NN*DD];    // E^T, staged at init

__global__ void bdh_init(const float* __restrict__ E) {
  const int gid = blockIdx.x * NTH + threadIdx.x;
  if (gid < NB) g_flag[gid].v = 0u;
  for (int idx = gid; idx < NN * DD; idx += 64 * NTH) {
    const int n = idx >> 6, d = idx & 63;
    g_ET[idx] = E[(size_t)d * NN + n];
  }
}

// ---- coherence-point (sc0 sc1) access helpers: bypass L1/L2, no fences ----
__device__ __forceinline__ void st_coh_f32(float* p, float v) {
  asm volatile("global_store_dword %0, %1, off sc0 sc1" :: "v"(p), "v"(v) : "memory");
}
__device__ __forceinline__ void st_coh_u32(unsigned* p, unsigned v) {
  asm volatile("global_store_dword %0, %1, off sc0 sc1" :: "v"(p), "v"(v) : "memory");
}
__device__ __forceinline__ void st_coh_f64(double* p, double v) {
  asm volatile("global_store_dwordx2 %0, %1, off sc0 sc1" :: "v"(p), "v"(v) : "memory");
}

// Fence-free split grid barrier (r7-proven memory discipline).
__device__ __forceinline__ void bar_arrive(unsigned& epoch) {
  epoch += 1u;
  asm volatile("s_waitcnt vmcnt(0)" ::: "memory");
  __syncthreads();
  if (threadIdx.x == 0)
    __hip_atomic_store(&g_flag[blockIdx.x].v, epoch, __ATOMIC_RELAXED,
                       __HIP_MEMORY_SCOPE_AGENT);
}
__device__ __forceinline__ void bar_wait(unsigned epoch) {
  if (threadIdx.x < 64) {
    const int i = (int)threadIdx.x;
    for (;;) {
      const bool ok = (i >= NB) ||
        (__hip_atomic_load(&g_flag[i].v, __ATOMIC_RELAXED,
                           __HIP_MEMORY_SCOPE_AGENT) >= epoch);
      if (__all(ok)) break;
      __builtin_amdgcn_s_sleep(1);
    }
  }
  __syncthreads();
}

__device__ __forceinline__ double wredd(double v) {
  #pragma unroll
  for (int off = 32; off > 0; off >>= 1) v += __shfl_xor(v, off, 64);
  return v;
}
__device__ __forceinline__ float wredf(float v) {
  #pragma unroll
  for (int off = 32; off > 0; off >>= 1) v += __shfl_xor(v, off, 64);
  return v;
}

// Wave-redundant crossing search over a plain 256-bin histogram: returns
// (bin, rem) where bin is the largest with suffix>=remK, rem = remK -
// suffix(>bin). No internal syncs; all threads return the same value.
__device__ __forceinline__ uint2 scan256h(const unsigned* __restrict__ h, int lane,
                                          unsigned remK) {
  const uint4 cc = ((const uint4*)h)[lane];
  unsigned c[4] = {cc.x, cc.y, cc.z, cc.w};
  unsigned s[4];
  s[3] = c[3]; s[2] = c[2] + s[3]; s[1] = c[1] + s[2]; s[0] = c[0] + s[1];
  unsigned SS = s[0];
  #pragma unroll
  for (int off = 1; off < 64; off <<= 1) {
    const unsigned o = __shfl_down(SS, off, 64);
    if (lane + off < 64) SS += o;
  }
  const unsigned T = SS - s[0];
  unsigned pk = 0u;
  #pragma unroll
  for (int k = 0; k < 4; ++k) {
    const unsigned A = s[k] + T;
    if (A >= remK && (A - c[k]) < remK)
      pk = (((unsigned)(4 * lane + k)) << 16) | (remK - (A - c[k]));
  }
  const unsigned long long bal = __ballot(pk != 0u);
  const int src = __ffsll((long long)bal) - 1;   // unique crossing lane
  pk = __shfl(pk, src, 64);
  return make_uint2(pk >> 16, pk & 0xffffu);
}

// Stable tie mask: keep keys > thr plus first R (by global index) == thr.
// One internal __syncthreads (uses cw[0..3]).
__device__ __forceinline__ unsigned tie_mask(const unsigned* __restrict__ keys,
                                             unsigned thr, unsigned R, int tid,
                                             unsigned* __restrict__ cw) {
  const int wv = tid >> 6, lane = tid & 63;
  unsigned lc[8], cnt = 0u;
  #pragma unroll
  for (int j = 0; j < 8; ++j) { lc[j] = cnt; cnt += (keys[j] == thr) ? 1u : 0u; }
  unsigned e = cnt;
  #pragma unroll
  for (int off = 1; off < 64; off <<= 1) {
    const unsigned o = __shfl_up(e, off, 64);
    if (lane >= off) e += o;
  }
  if (lane == 63) cw[wv] = e;
  __syncthreads();
  unsigned base = 0u;
  for (int w = 0; w < wv; ++w) base += cw[w];
  const unsigned excl = base + e - cnt;
  unsigned mask = 0u;
  #pragma unroll
  for (int j = 0; j < 8; ++j)
    if (keys[j] > thr || (keys[j] == thr && excl + lc[j] < R)) mask |= 1u << j;
  return mask;
}

// Exchange-based top-K: L0 comes PRE-REDUCED in h0 (per-block histogram
// exchange); levels 1-3 use plain per-level buffers (sparse survivors ->
// low contention, no reduce pass, 1 sync/level). PRE: h1,h2,h3 zeroed;
// caller zeroes them after return (tie sync makes that safe).
__device__ __forceinline__ unsigned select_exch(const unsigned* __restrict__ keys,
                                                int K, int tid,
                                                const unsigned* __restrict__ h0,
                                                unsigned* __restrict__ h1,
                                                unsigned* __restrict__ h2,
                                                unsigned* __restrict__ h3,
                                                unsigned* __restrict__ cw) {
  const int lane = tid & 63;
  uint2 r = scan256h(h0, lane, (unsigned)K);
  unsigned pre = r.x; unsigned remK = r.y;
  #pragma unroll
  for (int j = 0; j < 8; ++j)
    if ((keys[j] >> 24) == pre) atomicAdd(&h1[(keys[j] >> 16) & 255u], 1u);
  __syncthreads();
  r = scan256h(h1, lane, remK); pre = (pre << 8) | r.x; remK = r.y;
  #pragma unroll
  for (int j = 0; j < 8; ++j)
    if ((keys[j] >> 16) == pre) atomicAdd(&h2[(keys[j] >> 8) & 255u], 1u);
  __syncthreads();
  r = scan256h(h2, lane, remK); pre = (pre << 8) | r.x; remK = r.y;
  #pragma unroll
  for (int j = 0; j < 8; ++j)
    if ((keys[j] >> 8) == pre) atomicAdd(&h3[keys[j] & 255u], 1u);
  __syncthreads();
  r = scan256h(h3, lane, remK);
  const unsigned thr = (pre << 8) | r.x;
  return tie_mask(keys, thr, r.y, tid, cw);
}

__global__ void __launch_bounds__(NTH)
bdh_main(const int* __restrict__ tokens, const float* __restrict__ spike_u,
         const float* __restrict__ Emat, const float* __restrict__ Dx,
         const float* __restrict__ Dy, const float* __restrict__ temb,
         float* __restrict__ out)
{
  __shared__ float sh_rho[DD][PB];   // [d][local col]
  __shared__ float sh_Dx[CH][PA];    // [local neuron][d]
  __shared__ float sh_Dy[CH][PA];
  __shared__ int   sh_tok[TT];
  __shared__ float sh_v[2][DD];
  __shared__ float sh_xstate[CH];
  __shared__ float sh_xtun[CH];
  __shared__ float sh_ahat[DD];
  __shared__ float sh_ffac[CH];
  __shared__ __align__(16) unsigned sh_lh[256];    // local y L0 histogram
  __shared__ __align__(16) unsigned sh_lhx[256];   // local x L0 histogram
  __shared__ __align__(16) unsigned sh_h2y[256];   // summed global y L0
  __shared__ __align__(16) unsigned sh_h2x[256];   // summed global x L0
  __shared__ __align__(16) unsigned sh_hl1[256];   // shared levels 1-3 (plain)
  __shared__ __align__(16) unsigned sh_hl2[256];
  __shared__ __align__(16) unsigned sh_hl3[256];
  __shared__ unsigned sh_cw[8];
  __shared__ float sh_fmisc[4];
  __shared__ double sh_dred[8];
  __shared__ float sh_gred[4][DD];
  __shared__ int   sh_aidx[KWTA];
  __shared__ float sh_aw[KWTA];

  const int tid  = threadIdx.x;
  const int b    = blockIdx.x;
  const int n0   = b * CH;
  const int i2   = tid >> 1;   // local neuron row (0..127), Dx/Dy mapping
  const int p2   = tid & 1;    // half-split of 64-dot
  const int d4   = tid >> 2;   // d row (0..63), rho mapping
  const int p4   = tid & 3;    // quarter-comb of 128-dot
  const int lane = tid & 63;
  const int wv   = tid >> 6;
  unsigned epoch = 0u;

  // ---- one-time init: tokens, rho=0, hists=0, weight slices -> LDS ----
  for (int k = tid; k < TT; k += NTH) sh_tok[k] = tokens[k];
  for (int k = tid; k < DD*PB; k += NTH) (&sh_rho[0][0])[k] = 0.0f;
  sh_lh[tid] = 0u; sh_lhx[tid] = 0u;
  sh_hl1[tid] = 0u; sh_hl2[tid] = 0u; sh_hl3[tid] = 0u;
  if (tid < CH) sh_xstate[tid] = 0.0f;
  for (int r = wv; r < CH; r += 4) {
    sh_Dx[r][lane] = Dx[(size_t)(n0 + r)*DD + lane];
    sh_Dy[r][lane] = Dy[(size_t)(n0 + r)*DD + lane];
  }
  __syncthreads();
  if (tid < DD) sh_v[0][tid] = temb[(size_t)sh_tok[0]*DD + tid];
  __syncthreads();

  for (int t = 0; t < TT; ++t) {
    const int par = t & 1;

    // -------- phase 1: x_t (unnorm), L1 wave-partials, rho@x partial ------
    float spu = 0.0f;
    if (p2 == 0) spu = spike_u[(size_t)t*NN + n0 + i2];   // used in phase 2
    if (t + 1 < TT && tid < DD)
      sh_v[par ^ 1][tid] = temb[(size_t)sh_tok[t + 1]*DD + tid];

    float d1 = 0.0f;
    {
      const float* dxr = &sh_Dx[i2][p2*32];
      const float* vv  = &sh_v[par][p2*32];
      #pragma unroll
      for (int j = 0; j < 32; ++j) d1 += dxr[j] * vv[j];
    }
    d1 += __shfl_xor(d1, 1, 64);
    float xnew = 0.0f;
    if (p2 == 0) {
      xnew = 0.97f * sh_xstate[i2] + fmaxf(d1, 0.0f);
      sh_xtun[i2] = xnew;
      st_coh_f32(&g_xg[n0 + i2], xnew);      // publish UNNORMALIZED at A
    }
    {  // per-WAVE L1 partial published directly (no LDS round trip)
      double v = (p2 == 0) ? (double)fabsf(xnew) : 0.0;
      v = wredd(v);
      if (lane == 0) st_coh_f64(&g_L1w[b*4 + wv], v);
    }
    __syncthreads();   // REQUIRED: publish sh_xtun (all waves) before rho@x
    float qa = 0.0f;   // (rho @ x_un) partial over this block's 128 cols
    {
      const float* rr = &sh_rho[d4][0];
      #pragma unroll
      for (int j = 0; j < 32; ++j) { const int c = p4 + 4*j; qa += rr[c] * sh_xtun[c]; }
    }
    qa += __shfl_xor(qa, 1, 64);
    qa += __shfl_xor(qa, 2, 64);
    if (p4 == 0) st_coh_f32(&g_rfT[d4][b], qa);   // transposed: [d][block]
    bar_arrive(epoch);                       // ========== A ==========
    bar_wait(epoch);

    // -------- phase 2: one batched coherent read (x, rfT, L1w) ------------
    f32x4 xu0, xu1, r0, r1, r2, r3; double lv;
    {
      const float*  xp = g_xg + tid*8;
      const float*  rp = &g_rfT[lane][0];    // this lane's d = lane
      const double* lp = &g_L1w[lane];
      asm volatile(
        "global_load_dwordx4 %0, %7, off sc0 sc1\n\t"
        "global_load_dwordx4 %1, %7, off offset:16 sc0 sc1\n\t"
        "global_load_dwordx4 %2, %8, off sc0 sc1\n\t"
        "global_load_dwordx4 %3, %8, off offset:16 sc0 sc1\n\t"
        "global_load_dwordx4 %4, %8, off offset:32 sc0 sc1\n\t"
        "global_load_dwordx4 %5, %8, off offset:48 sc0 sc1\n\t"
        "global_load_dwordx2 %6, %9, off sc0 sc1\n\t"
        "s_waitcnt vmcnt(0)"
        : "=&v"(xu0), "=&v"(xu1), "=&v"(r0), "=&v"(r1), "=&v"(r2), "=&v"(r3),
          "=&v"(lv)
        : "v"(xp), "v"(rp), "v"(lp)
        : "memory");
      __builtin_amdgcn_sched_barrier(0);
    }
    // L1 total redundantly per-wave, in registers (bit-identical Lden).
    const double L1tot = wredd(lv);          // 64 wave-partials
    const float Lden = (float)L1tot + 1e-6f;
    unsigned xkeys[8];   // normalized-x keys, identical in every block
    {
      const float xf[8] = {xu0[0],xu0[1],xu0[2],xu0[3], xu1[0],xu1[1],xu1[2],xu1[3]};
      #pragma unroll
      for (int j = 0; j < 8; ++j) xkeys[j] = __float_as_uint(xf[j] / Lden);
    }
    // local x L0 histogram (128 atomics, own value; bit-identical to xkeys)
    if (p2 == 0)
      atomicAdd(&sh_lhx[__float_as_uint(xnew / Lden) >> 24], 1u);
    // a_hat LN: EVERY wave redundantly for d = lane (r16 summation grouping);
    // all waves write identical bits to sh_ahat[lane] (benign same-value race)
    {
      double a0 = 0.0, a1 = 0.0, a2 = 0.0, a3 = 0.0;
      a0 += (double)r0[0]; a0 += (double)r0[1]; a0 += (double)r0[2]; a0 += (double)r0[3];
      a1 += (double)r1[0]; a1 += (double)r1[1]; a1 += (double)r1[2]; a1 += (double)r1[3];
      a2 += (double)r2[0]; a2 += (double)r2[1]; a2 += (double)r2[2]; a2 += (double)r2[3];
      a3 += (double)r3[0]; a3 += (double)r3[1]; a3 += (double)r3[2]; a3 += (double)r3[3];
      const double qd = ((a0 + a1) + a2) + a3;
      const float rff = (float)qd / Lden;
      const float mm = wredf(rff) * (1.0f/64.0f);
      const float dvv = rff - mm;
      const float sd = sqrtf(wredf(dvv*dvv) * (1.0f/63.0f));   // ddof=1
      sh_ahat[lane] = dvv / (sd + 1e-6f);
    }
    __syncthreads();                         // a_hat ready for all rows
    float d2 = 0.0f;
    {
      const float* dyr = &sh_Dy[i2][p2*32];
      const float* aa  = &sh_ahat[p2*32];
      #pragma unroll
      for (int j = 0; j < 32; ++j) d2 += dyr[j] * aa[j];
    }
    d2 += __shfl_xor(d2, 1, 64);
    if (p2 == 0) {
      const float sp = fmaxf(d2, 0.0f) + log1pf(expf(-fabsf(d2)));  // softplus
      const float yv = sp + ((spu < 0.01f) ? 1.0f : 0.0f);
      st_coh_f32(&g_yg[n0 + i2], yv);
      atomicAdd(&sh_lh[__float_as_uint(yv) >> 24], 1u);   // local y L0 hist
    }
    __syncthreads();
    {  // publish local L0 histograms; re-zero for next step (owner r/w, safe)
      const unsigned cy = sh_lh[tid];
      const unsigned cx = sh_lhx[tid];
      sh_lh[tid] = 0u; sh_lhx[tid] = 0u;
      st_coh_u32(&g_yh[b][tid], cy);
      st_coh_u32(&g_xh[b][tid], cx);
    }
    bar_arrive(epoch);                       // ========== B ==========
    bar_wait(epoch);

    // -------- phase 3 (barrier-free): selects, gather, update -------------
    // issue the 32 per-block L0 histogram loads first (drained by the asm's
    // vmcnt(0) below), then the ykeys batch.
    unsigned yh[NB], xh[NB];
    #pragma unroll
    for (int bb = 0; bb < NB; ++bb) {
      yh[bb] = __hip_atomic_load(&g_yh[bb][tid], __ATOMIC_RELAXED,
                                 __HIP_MEMORY_SCOPE_AGENT);
      xh[bb] = __hip_atomic_load(&g_xh[bb][tid], __ATOMIC_RELAXED,
                                 __HIP_MEMORY_SCOPE_AGENT);
    }
    unsigned ykeys[8];
    {
      f32x4 yv0, yv1;
      const float* yp = g_yg + tid*8;
      asm volatile(
        "global_load_dwordx4 %0, %2, off sc0 sc1\n\t"
        "global_load_dwordx4 %1, %2, off offset:16 sc0 sc1\n\t"
        "s_waitcnt vmcnt(0)"
        : "=&v"(yv0), "=&v"(yv1) : "v"(yp) : "memory");
      __builtin_amdgcn_sched_barrier(0);
      ykeys[0]=__float_as_uint(yv0[0]); ykeys[1]=__float_as_uint(yv0[1]);
      ykeys[2]=__float_as_uint(yv0[2]); ykeys[3]=__float_as_uint(yv0[3]);
      ykeys[4]=__float_as_uint(yv1[0]); ykeys[5]=__float_as_uint(yv1[1]);
      ykeys[6]=__float_as_uint(yv1[2]); ykeys[7]=__float_as_uint(yv1[3]);
    }
    {
      unsigned hsy = 0u, hsx = 0u;
      #pragma unroll
      for (int bb = 0; bb < NB; ++bb) { hsy += yh[bb]; hsx += xh[bb]; }
      sh_h2y[tid] = hsy;                     // global y L0 histogram
      sh_h2x[tid] = hsx;                     // global x L0 histogram
    }
    __syncthreads();
    // k-WTA keep mask (L0 prebuilt via exchange; levels 1-3 plain)
    const unsigned km = select_exch(ykeys, KWTA, tid, sh_h2y,
                                    sh_hl1, sh_hl2, sh_hl3, sh_cw);
    // zero plain level buffers for reuse by x-select (tie sync => scans done)
    sh_hl1[tid] = 0u; sh_hl2[tid] = 0u; sh_hl3[tid] = 0u;
    // y_t products + nonzero flags (y > 0 always; nz iff kept and x > 0)
    float p[8]; unsigned nzm = 0u;
    #pragma unroll
    for (int j = 0; j < 8; ++j) {
      const float yv = __uint_as_float(ykeys[j]);
      const float xv = __uint_as_float(xkeys[j]);
      p[j] = yv * xv;
      if (((km >> j) & 1u) && xv > 0.0f) nzm |= 1u << j;
    }
    const unsigned cnt = (unsigned)__popc(nzm);
    // s = sum(y_t) (f64), and compaction offsets — one shared sync
    {
      double sp = 0.0;
      #pragma unroll
      for (int j = 0; j < 8; ++j) if ((nzm >> j) & 1u) sp += (double)p[j];
      sp = wredd(sp);
      if (lane == 0) sh_dred[wv] = sp;
    }
    unsigned e = cnt;
    #pragma unroll
    for (int off = 1; off < 64; off <<= 1) {
      const unsigned o = __shfl_up(e, off, 64);
      if (lane >= off) e += o;
    }
    if (lane == 63) sh_cw[4 + wv] = e;
    __syncthreads();
    const float sf = (float)(sh_dred[0] + sh_dred[1] + sh_dred[2] + sh_dred[3]);
    const float scale = (sf > 1e-8f) ? fminf(1.0f, 1.0f/(sf + 1e-8f)) : 1.0f;
    const int m = (int)(sh_cw[4] + sh_cw[5] + sh_cw[6] + sh_cw[7]);
    {
      unsigned base = 0u;
      for (int w = 0; w < wv; ++w) base += sh_cw[4 + w];
      int pos = (int)(base + e - cnt);
      #pragma unroll
      for (int j = 0; j < 8; ++j)
        if ((nzm >> j) & 1u) { sh_aidx[pos] = 8*tid + j; sh_aw[pos] = scale * p[j]; ++pos; }
    }
    __syncthreads();
    // sparse gather-matvec: v_pre[d] = sum_i w_i * ET[idx_i][d]; 4 ILP chains
    {
      float a0 = 0.0f, a1 = 0.0f, a2 = 0.0f, a3 = 0.0f;
      int i = wv;
      for (; i + 12 < m; i += 16) {
        a0 = fmaf(sh_aw[i],      g_ET[(size_t)sh_aidx[i]     *DD + lane], a0);
        a1 = fmaf(sh_aw[i + 4],  g_ET[(size_t)sh_aidx[i + 4] *DD + lane], a1);
        a2 = fmaf(sh_aw[i + 8],  g_ET[(size_t)sh_aidx[i + 8] *DD + lane], a2);
        a3 = fmaf(sh_aw[i + 12], g_ET[(size_t)sh_aidx[i + 12]*DD + lane], a3);
      }
      for (; i < m; i += 4)
        a0 = fmaf(sh_aw[i], g_ET[(size_t)sh_aidx[i]*DD + lane], a0);
      sh_gred[wv][lane] = (a0 + a1) + (a2 + a3);
    }
    __syncthreads();
    // LN + entropy + gain (wave 0), all blocks redundantly -> identical
    if (tid < 64) {
      const float z = sh_gred[0][tid] + sh_gred[1][tid] + sh_gred[2][tid] + sh_gred[3][tid];
      const float mn = wredf(z) * (1.0f/64.0f);
      const float dv = z - mn;
      const float sd = sqrtf(wredf(dv*dv) * (1.0f/63.0f));
      const float vs = dv / (sd + 1e-6f);
      if (b == 0) out[t*DD + tid] = vs;
      float mx = vs;
      #pragma unroll
      for (int off = 32; off > 0; off >>= 1) mx = fmaxf(mx, __shfl_xor(mx, off, 64));
      const float ex = expf(vs - mx);
      const float se = wredf(ex);
      const float pp = ex / se;
      const float ht = wredf(-pp * logf(pp + 1e-12f));
      if (tid == 0) sh_fmisc[0] = fminf(1.0f, ht / logf(64.0f));
    }
    __syncthreads();
    const float gain = sh_fmisc[0];
    int kdi = (int)(2048.0f * (0.05f + 0.25f * gain));
    kdi = kdi < 1 ? 1 : (kdi > NN ? NN : kdi);
    // dynamic top-k on x (L0 prebuilt via exchange; levels 1-3 plain, reused)
    const unsigned xm = select_exch(xkeys, kdi, tid, sh_h2x,
                                    sh_hl1, sh_hl2, sh_hl3, sh_cw);
    // zero plain level buffers for next step's y-select
    sh_hl1[tid] = 0u; sh_hl2[tid] = 0u; sh_hl3[tid] = 0u;
    #pragma unroll
    for (int j = 0; j < 8; ++j) {
      const int g = 8*tid + j;
      const unsigned l = (unsigned)(g - n0);
      if (l < (unsigned)CH) {
        const float xv = __uint_as_float(xkeys[j]);
        const float v = ((xm >> j) & 1u) ? xv : 0.0f;
        sh_xstate[l] = v;
        sh_ffac[l] = (v <= 0.0f) ? (1.0f - 0.01f) : 1.0f;
      }
    }
    __syncthreads();
    {
      const float vd = sh_v[par][d4];
      float* rr = &sh_rho[d4][0];
      #pragma unroll
      for (int j = 0; j < 32; ++j) {
        const int c = p4 + 4*j;
        rr[c] = 0.97f * (rr[c]*sh_ffac[c] + gain * (vd * sh_xstate[c]));
      }
    }
    __syncthreads();   // protect sh_v/sh_xstate/rho before next iteration
  }
}

extern "C" void kernel_launch(void* const* d_in, const int* in_sizes, int n_in,
                              void* d_out, int out_size, void* d_ws, size_t ws_size,
                              hipStream_t stream) {
  const int*   tokens = (const int*)d_in[0];
  const float* spike  = (const float*)d_in[1];
  const float* Emat   = (const float*)d_in[2];
  const float* Dx     = (const float*)d_in[3];
  const float* Dy     = (const float*)d_in[4];
  const float* temb   = (const float*)d_in[5];
  float* out = (float*)d_out;
  (void)in_sizes; (void)n_in; (void)out_size; (void)d_ws; (void)ws_size;
  bdh_init<<<dim3(64), dim3(NTH), 0, stream>>>(Emat);
  bdh_main<<<dim3(NB), dim3(NTH), 0, stream>>>(tokens, spike, Emat, Dx, Dy, temb, out);
}

// Round 19
// 9320.698 us; speedup vs baseline: 1.0217x; 1.0217x over previous
//
#include <hip/hip_runtime.h>
#include <math.h>

#define NB   16      // blocks
#define NTH  256     // threads per block
#define CH   128     // neurons per block (N/NB)
#define NN   2048    // N
#define DD   64      // D
#define TT   512     // T
#define KWTA 256
#define PA   65      // pad for [CH][64+1] rows (Dx, Dy)
#define PB   132     // pad for [64][128+4] rows (rho), comb access 2-way-free

typedef float f32x4 __attribute__((ext_vector_type(4)));

// ---- cross-block communication (single-buffered; WAR-safe by barrier deps) --
struct __align__(128) BarFlag { unsigned v; unsigned pad[31]; };
__device__ BarFlag g_flag[NB];
__device__ __align__(16) float    g_rf[NB][DD];   // rho@x_un partials
__device__ __align__(16) double   g_L1[NB];
__device__ __align__(16) float    g_xg[NN];       // UNNORMALIZED xtun (at A)
__device__ __align__(16) float    g_yg[NN];
__device__ __align__(16) unsigned g_yh[NB][256];  // per-block y L0 histograms
__device__ __align__(16) unsigned g_xh[NB][256];  // per-block x L0 histograms
__device__ __align__(16) float    g_ET[NN*DD];    // E^T, staged at init

__global__ void bdh_init(const float* __restrict__ E) {
  const int gid = blockIdx.x * NTH + threadIdx.x;
  if (gid < NB) g_flag[gid].v = 0u;
  for (int idx = gid; idx < NN * DD; idx += 64 * NTH) {
    const int n = idx >> 6, d = idx & 63;
    g_ET[idx] = E[(size_t)d * NN + n];
  }
}

// ---- coherence-point (sc0 sc1) access helpers: bypass L1/L2, no fences ----
__device__ __forceinline__ void st_coh_f32(float* p, float v) {
  asm volatile("global_store_dword %0, %1, off sc0 sc1" :: "v"(p), "v"(v) : "memory");
}
__device__ __forceinline__ void st_coh_u32(unsigned* p, unsigned v) {
  asm volatile("global_store_dword %0, %1, off sc0 sc1" :: "v"(p), "v"(v) : "memory");
}
__device__ __forceinline__ void st_coh_f64(double* p, double v) {
  asm volatile("global_store_dwordx2 %0, %1, off sc0 sc1" :: "v"(p), "v"(v) : "memory");
}

// Fence-free split grid barrier (r7-proven memory discipline).
__device__ __forceinline__ void bar_arrive(unsigned& epoch) {
  epoch += 1u;
  asm volatile("s_waitcnt vmcnt(0)" ::: "memory");
  __syncthreads();
  if (threadIdx.x == 0)
    __hip_atomic_store(&g_flag[blockIdx.x].v, epoch, __ATOMIC_RELAXED,
                       __HIP_MEMORY_SCOPE_AGENT);
}
__device__ __forceinline__ void bar_wait(unsigned epoch) {
  if (threadIdx.x < 64) {
    const int i = (int)threadIdx.x;
    for (;;) {
      const bool ok = (i >= NB) ||
        (__hip_atomic_load(&g_flag[i].v, __ATOMIC_RELAXED,
                           __HIP_MEMORY_SCOPE_AGENT) >= epoch);
      if (__all(ok)) break;
      __builtin_amdgcn_s_sleep(1);
    }
  }
  __syncthreads();
}

__device__ __forceinline__ double wredd(double v) {
  #pragma unroll
  for (int off = 32; off > 0; off >>= 1) v += __shfl_xor(v, off, 64);
  return v;
}
__device__ __forceinline__ float wredf(float v) {
  #pragma unroll
  for (int off = 32; off > 0; off >>= 1) v += __shfl_xor(v, off, 64);
  return v;
}

// Wave-redundant crossing search over a plain 256-bin histogram: returns
// (bin, rem) where bin is the largest with suffix>=remK, rem = remK -
// suffix(>bin). No internal syncs; all threads return the same value.
__device__ __forceinline__ uint2 scan256h(const unsigned* __restrict__ h, int lane,
                                          unsigned remK) {
  const uint4 cc = ((const uint4*)h)[lane];
  unsigned c[4] = {cc.x, cc.y, cc.z, cc.w};
  unsigned s[4];
  s[3] = c[3]; s[2] = c[2] + s[3]; s[1] = c[1] + s[2]; s[0] = c[0] + s[1];
  unsigned SS = s[0];
  #pragma unroll
  for (int off = 1; off < 64; off <<= 1) {
    const unsigned o = __shfl_down(SS, off, 64);
    if (lane + off < 64) SS += o;
  }
  const unsigned T = SS - s[0];
  unsigned pk = 0u;
  #pragma unroll
  for (int k = 0; k < 4; ++k) {
    const unsigned A = s[k] + T;
    if (A >= remK && (A - c[k]) < remK)
      pk = (((unsigned)(4 * lane + k)) << 16) | (remK - (A - c[k]));
  }
  const unsigned long long bal = __ballot(pk != 0u);
  const int src = __ffsll((long long)bal) - 1;   // unique crossing lane
  pk = __shfl(pk, src, 64);
  return make_uint2(pk >> 16, pk & 0xffffu);
}

// Stable tie mask: keep keys > thr plus first R (by global index) == thr.
// One internal __syncthreads (uses cw[0..3]).
__device__ __forceinline__ unsigned tie_mask(const unsigned* __restrict__ keys,
                                             unsigned thr, unsigned R, int tid,
                                             unsigned* __restrict__ cw) {
  const int wv = tid >> 6, lane = tid & 63;
  unsigned lc[8], cnt = 0u;
  #pragma unroll
  for (int j = 0; j < 8; ++j) { lc[j] = cnt; cnt += (keys[j] == thr) ? 1u : 0u; }
  unsigned e = cnt;
  #pragma unroll
  for (int off = 1; off < 64; off <<= 1) {
    const unsigned o = __shfl_up(e, off, 64);
    if (lane >= off) e += o;
  }
  if (lane == 63) cw[wv] = e;
  __syncthreads();
  unsigned base = 0u;
  for (int w = 0; w < wv; ++w) base += cw[w];
  const unsigned excl = base + e - cnt;
  unsigned mask = 0u;
  #pragma unroll
  for (int j = 0; j < 8; ++j)
    if (keys[j] > thr || (keys[j] == thr && excl + lc[j] < R)) mask |= 1u << j;
  return mask;
}

// Exchange-based top-K: L0 comes PRE-REDUCED in h0 (per-block histogram
// exchange); levels 1-3 use plain per-level buffers (sparse survivors ->
// low contention, no reduce pass, 1 sync/level). PRE: h1,h2,h3 zeroed;
// caller zeroes them after return (tie sync makes that safe).
__device__ __forceinline__ unsigned select_exch(const unsigned* __restrict__ keys,
                                                int K, int tid,
                                                const unsigned* __restrict__ h0,
                                                unsigned* __restrict__ h1,
                                                unsigned* __restrict__ h2,
                                                unsigned* __restrict__ h3,
                                                unsigned* __restrict__ cw) {
  const int lane = tid & 63;
  uint2 r = scan256h(h0, lane, (unsigned)K);
  unsigned pre = r.x; unsigned remK = r.y;
  #pragma unroll
  for (int j = 0; j < 8; ++j)
    if ((keys[j] >> 24) == pre) atomicAdd(&h1[(keys[j] >> 16) & 255u], 1u);
  __syncthreads();
  r = scan256h(h1, lane, remK); pre = (pre << 8) | r.x; remK = r.y;
  #pragma unroll
  for (int j = 0; j < 8; ++j)
    if ((keys[j] >> 16) == pre) atomicAdd(&h2[(keys[j] >> 8) & 255u], 1u);
  __syncthreads();
  r = scan256h(h2, lane, remK); pre = (pre << 8) | r.x; remK = r.y;
  #pragma unroll
  for (int j = 0; j < 8; ++j)
    if ((keys[j] >> 8) == pre) atomicAdd(&h3[keys[j] & 255u], 1u);
  __syncthreads();
  r = scan256h(h3, lane, remK);
  const unsigned thr = (pre << 8) | r.x;
  return tie_mask(keys, thr, r.y, tid, cw);
}

__global__ void __launch_bounds__(NTH)
bdh_main(const int* __restrict__ tokens, const float* __restrict__ spike_u,
         const float* __restrict__ Emat, const float* __restrict__ Dx,
         const float* __restrict__ Dy, const float* __restrict__ temb,
         float* __restrict__ out)
{
  __shared__ float sh_rho[DD][PB];   // [d][local col]
  __shared__ float sh_Dx[CH][PA];    // [local neuron][d]
  __shared__ float sh_Dy[CH][PA];
  __shared__ int   sh_tok[TT];
  __shared__ float sh_v[2][DD];
  __shared__ float sh_xstate[CH];
  __shared__ float sh_xtun[CH];
  __shared__ float sh_ahat[DD];
  __shared__ float sh_ffac[CH];
  __shared__ __align__(16) unsigned sh_lh[256];    // local y L0 histogram
  __shared__ __align__(16) unsigned sh_lhx[256];   // local x L0 histogram
  __shared__ __align__(16) unsigned sh_h2y[256];   // summed global y L0
  __shared__ __align__(16) unsigned sh_h2x[256];   // summed global x L0
  __shared__ __align__(16) unsigned sh_hl1[256];   // shared levels 1-3 (plain)
  __shared__ __align__(16) unsigned sh_hl2[256];
  __shared__ __align__(16) unsigned sh_hl3[256];
  __shared__ unsigned sh_cw[8];
  __shared__ float sh_fmisc[4];
  __shared__ double sh_dred[8];
  __shared__ double sh_rd[4][DD];
  __shared__ float sh_gred[4][DD];
  __shared__ int   sh_aidx[KWTA];
  __shared__ float sh_aw[KWTA];

  const int tid  = threadIdx.x;
  const int b    = blockIdx.x;
  const int n0   = b * CH;
  const int i2   = tid >> 1;   // local neuron row (0..127), Dx/Dy mapping
  const int p2   = tid & 1;    // half-split of 64-dot
  const int d4   = tid >> 2;   // d row (0..63), rho mapping
  const int p4   = tid & 3;    // quarter-comb of 128-dot
  const int lane = tid & 63;
  const int wv   = tid >> 6;
  unsigned epoch = 0u;

  // ---- one-time init: tokens, rho=0, hists=0, weight slices -> LDS ----
  for (int k = tid; k < TT; k += NTH) sh_tok[k] = tokens[k];
  for (int k = tid; k < DD*PB; k += NTH) (&sh_rho[0][0])[k] = 0.0f;
  sh_lh[tid] = 0u; sh_lhx[tid] = 0u;
  sh_hl1[tid] = 0u; sh_hl2[tid] = 0u; sh_hl3[tid] = 0u;
  if (tid < CH) sh_xstate[tid] = 0.0f;
  for (int r = wv; r < CH; r += 4) {
    sh_Dx[r][lane] = Dx[(size_t)(n0 + r)*DD + lane];
    sh_Dy[r][lane] = Dy[(size_t)(n0 + r)*DD + lane];
  }
  __syncthreads();
  if (tid < DD) sh_v[0][tid] = temb[(size_t)sh_tok[0]*DD + tid];
  __syncthreads();

  for (int t = 0; t < TT; ++t) {
    const int par = t & 1;

    // -------- phase 1: x_t (unnorm), L1 partial, rho@x partial ------------
    float spu = 0.0f;
    if (p2 == 0) spu = spike_u[(size_t)t*NN + n0 + i2];   // used in phase 2
    if (t + 1 < TT && tid < DD)
      sh_v[par ^ 1][tid] = temb[(size_t)sh_tok[t + 1]*DD + tid];

    float d1 = 0.0f;
    {
      const float* dxr = &sh_Dx[i2][p2*32];
      const float* vv  = &sh_v[par][p2*32];
      #pragma unroll
      for (int j = 0; j < 32; ++j) d1 += dxr[j] * vv[j];
    }
    d1 += __shfl_xor(d1, 1, 64);
    float xnew = 0.0f;
    if (p2 == 0) {
      xnew = 0.97f * sh_xstate[i2] + fmaxf(d1, 0.0f);
      sh_xtun[i2] = xnew;
      st_coh_f32(&g_xg[n0 + i2], xnew);      // publish UNNORMALIZED at A
    }
    {
      double v = (p2 == 0) ? (double)fabsf(xnew) : 0.0;
      v = wredd(v);
      if (lane == 0) sh_dred[wv] = v;
      __syncthreads();
      if (tid == 0) st_coh_f64(&g_L1[b],
                               sh_dred[0] + sh_dred[1] + sh_dred[2] + sh_dred[3]);
    }
    float qa = 0.0f;   // (rho @ x_un) partial over this block's 128 cols
    {
      const float* rr = &sh_rho[d4][0];
      #pragma unroll
      for (int j = 0; j < 32; ++j) { const int c = p4 + 4*j; qa += rr[c] * sh_xtun[c]; }
    }
    qa += __shfl_xor(qa, 1, 64);
    qa += __shfl_xor(qa, 2, 64);
    if (p4 == 0) st_coh_f32(&g_rf[b][d4], qa);
    bar_arrive(epoch);                       // ========== A ==========
    bar_wait(epoch);

    // -------- phase 2: one batched coherent read (x, rf, L1), a_hat, y ----
    f32x4 xu0, xu1; float rf0, rf1, rf2, rf3; double lv;
    {
      const float*  xp = g_xg + tid*8;
      const float*  rp = &g_rf[wv*4][lane];
      const double* lp = &g_L1[lane & 15];
      asm volatile(
        "global_load_dwordx4 %0, %7, off sc0 sc1\n\t"
        "global_load_dwordx4 %1, %7, off offset:16 sc0 sc1\n\t"
        "global_load_dword %2, %8, off sc0 sc1\n\t"
        "global_load_dword %3, %8, off offset:256 sc0 sc1\n\t"
        "global_load_dword %4, %8, off offset:512 sc0 sc1\n\t"
        "global_load_dword %5, %8, off offset:768 sc0 sc1\n\t"
        "global_load_dwordx2 %6, %9, off sc0 sc1\n\t"
        "s_waitcnt vmcnt(0)"
        : "=&v"(xu0), "=&v"(xu1), "=&v"(rf0), "=&v"(rf1), "=&v"(rf2), "=&v"(rf3),
          "=&v"(lv)
        : "v"(xp), "v"(rp), "v"(lp)
        : "memory");
      __builtin_amdgcn_sched_barrier(0);
    }
    {
      double acc = 0.0;
      acc += (double)rf0; acc += (double)rf1; acc += (double)rf2; acc += (double)rf3;
      sh_rd[wv][lane] = acc;
    }
    // L1 total redundantly per-wave, in registers (bit-identical Lden).
    const double L1tot = wredd((lane < 16) ? lv : 0.0);
    const float Lden = (float)L1tot + 1e-6f;
    unsigned xkeys[8];   // normalized-x keys, identical in every block
    {
      const float xf[8] = {xu0[0],xu0[1],xu0[2],xu0[3], xu1[0],xu1[1],xu1[2],xu1[3]};
      #pragma unroll
      for (int j = 0; j < 8; ++j) xkeys[j] = __float_as_uint(xf[j] / Lden);
    }
    // local x L0 histogram (128 atomics, own value; bit-identical to xkeys)
    if (p2 == 0)
      atomicAdd(&sh_lhx[__float_as_uint(xnew / Lden) >> 24], 1u);
    __syncthreads();                         // publish sh_rd (and lhx order)
    if (tid < 64) {
      const double qd = sh_rd[0][tid] + sh_rd[1][tid] + sh_rd[2][tid] + sh_rd[3][tid];
      const float rf = (float)qd / Lden;
      const float mm = wredf(rf) * (1.0f/64.0f);
      const float dv = rf - mm;
      const float sd = sqrtf(wredf(dv*dv) * (1.0f/63.0f));   // ddof=1
      sh_ahat[tid] = dv / (sd + 1e-6f);
    }
    __syncthreads();
    float d2 = 0.0f;
    {
      const float* dyr = &sh_Dy[i2][p2*32];
      const float* aa  = &sh_ahat[p2*32];
      #pragma unroll
      for (int j = 0; j < 32; ++j) d2 += dyr[j] * aa[j];
    }
    d2 += __shfl_xor(d2, 1, 64);
    if (p2 == 0) {
      const float sp = fmaxf(d2, 0.0f) + log1pf(expf(-fabsf(d2)));  // softplus
      const float yv = sp + ((spu < 0.01f) ? 1.0f : 0.0f);
      st_coh_f32(&g_yg[n0 + i2], yv);
      atomicAdd(&sh_lh[__float_as_uint(yv) >> 24], 1u);   // local y L0 hist
    }
    __syncthreads();
    {  // publish local L0 histograms; re-zero for next step (owner r/w, safe)
      const unsigned cy = sh_lh[tid];
      const unsigned cx = sh_lhx[tid];
      sh_lh[tid] = 0u; sh_lhx[tid] = 0u;
      st_coh_u32(&g_yh[b][tid], cy);
      st_coh_u32(&g_xh[b][tid], cx);
    }
    bar_arrive(epoch);                       // ========== B ==========
    bar_wait(epoch);

    // -------- phase 3 (barrier-free): selects, gather, update -------------
    // issue the 32 per-block L0 histogram loads first (drained by the asm's
    // vmcnt(0) below), then the ykeys batch.
    unsigned yh[NB], xh[NB];
    #pragma unroll
    for (int bb = 0; bb < NB; ++bb) {
      yh[bb] = __hip_atomic_load(&g_yh[bb][tid], __ATOMIC_RELAXED,
                                 __HIP_MEMORY_SCOPE_AGENT);
      xh[bb] = __hip_atomic_load(&g_xh[bb][tid], __ATOMIC_RELAXED,
                                 __HIP_MEMORY_SCOPE_AGENT);
    }
    unsigned ykeys[8];
    {
      f32x4 yv0, yv1;
      const float* yp = g_yg + tid*8;
      asm volatile(
        "global_load_dwordx4 %0, %2, off sc0 sc1\n\t"
        "global_load_dwordx4 %1, %2, off offset:16 sc0 sc1\n\t"
        "s_waitcnt vmcnt(0)"
        : "=&v"(yv0), "=&v"(yv1) : "v"(yp) : "memory");
      __builtin_amdgcn_sched_barrier(0);
      ykeys[0]=__float_as_uint(yv0[0]); ykeys[1]=__float_as_uint(yv0[1]);
      ykeys[2]=__float_as_uint(yv0[2]); ykeys[3]=__float_as_uint(yv0[3]);
      ykeys[4]=__float_as_uint(yv1[0]); ykeys[5]=__float_as_uint(yv1[1]);
      ykeys[6]=__float_as_uint(yv1[2]); ykeys[7]=__float_as_uint(yv1[3]);
    }
    {
      unsigned hsy = 0u, hsx = 0u;
      #pragma unroll
      for (int bb = 0; bb < NB; ++bb) { hsy += yh[bb]; hsx += xh[bb]; }
      sh_h2y[tid] = hsy;                     // global y L0 histogram
      sh_h2x[tid] = hsx;                     // global x L0 histogram
    }
    __syncthreads();
    // k-WTA keep mask (L0 prebuilt via exchange; levels 1-3 plain)
    const unsigned km = select_exch(ykeys, KWTA, tid, sh_h2y,
                                    sh_hl1, sh_hl2, sh_hl3, sh_cw);
    // zero plain level buffers for reuse by x-select (tie sync => scans done)
    sh_hl1[tid] = 0u; sh_hl2[tid] = 0u; sh_hl3[tid] = 0u;
    // y_t products + nonzero flags (y > 0 always; nz iff kept and x > 0)
    float p[8]; unsigned nzm = 0u;
    #pragma unroll
    for (int j = 0; j < 8; ++j) {
      const float yv = __uint_as_float(ykeys[j]);
      const float xv = __uint_as_float(xkeys[j]);
      p[j] = yv * xv;
      if (((km >> j) & 1u) && xv > 0.0f) nzm |= 1u << j;
    }
    const unsigned cnt = (unsigned)__popc(nzm);
    // s = sum(y_t) (f64), and compaction offsets — one shared sync
    {
      double sp = 0.0;
      #pragma unroll
      for (int j = 0; j < 8; ++j) if ((nzm >> j) & 1u) sp += (double)p[j];
      sp = wredd(sp);
      if (lane == 0) sh_dred[wv] = sp;
    }
    unsigned e = cnt;
    #pragma unroll
    for (int off = 1; off < 64; off <<= 1) {
      const unsigned o = __shfl_up(e, off, 64);
      if (lane >= off) e += o;
    }
    if (lane == 63) sh_cw[4 + wv] = e;
    __syncthreads();
    const float sf = (float)(sh_dred[0] + sh_dred[1] + sh_dred[2] + sh_dred[3]);
    const float scale = (sf > 1e-8f) ? fminf(1.0f, 1.0f/(sf + 1e-8f)) : 1.0f;
    const int m = (int)(sh_cw[4] + sh_cw[5] + sh_cw[6] + sh_cw[7]);
    {
      unsigned base = 0u;
      for (int w = 0; w < wv; ++w) base += sh_cw[4 + w];
      int pos = (int)(base + e - cnt);
      #pragma unroll
      for (int j = 0; j < 8; ++j)
        if ((nzm >> j) & 1u) { sh_aidx[pos] = 8*tid + j; sh_aw[pos] = scale * p[j]; ++pos; }
    }
    __syncthreads();
    // sparse gather-matvec: v_pre[d] = sum_i w_i * ET[idx_i][d]; 4 ILP chains
    {
      float a0 = 0.0f, a1 = 0.0f, a2 = 0.0f, a3 = 0.0f;
      int i = wv;
      for (; i + 12 < m; i += 16) {
        a0 = fmaf(sh_aw[i],      g_ET[(size_t)sh_aidx[i]     *DD + lane], a0);
        a1 = fmaf(sh_aw[i + 4],  g_ET[(size_t)sh_aidx[i + 4] *DD + lane], a1);
        a2 = fmaf(sh_aw[i + 8],  g_ET[(size_t)sh_aidx[i + 8] *DD + lane], a2);
        a3 = fmaf(sh_aw[i + 12], g_ET[(size_t)sh_aidx[i + 12]*DD + lane], a3);
      }
      for (; i < m; i += 4)
        a0 = fmaf(sh_aw[i], g_ET[(size_t)sh_aidx[i]*DD + lane], a0);
      sh_gred[wv][lane] = (a0 + a1) + (a2 + a3);
    }
    __syncthreads();
    // LN + entropy + gain (wave 0), all blocks redundantly -> identical
    if (tid < 64) {
      const float z = sh_gred[0][tid] + sh_gred[1][tid] + sh_gred[2][tid] + sh_gred[3][tid];
      const float mn = wredf(z) * (1.0f/64.0f);
      const float dv = z - mn;
      const float sd = sqrtf(wredf(dv*dv) * (1.0f/63.0f));
      const float vs = dv / (sd + 1e-6f);
      if (b == 0) out[t*DD + tid] = vs;
      float mx = vs;
      #pragma unroll
      for (int off = 32; off > 0; off >>= 1) mx = fmaxf(mx, __shfl_xor(mx, off, 64));
      const float ex = expf(vs - mx);
      const float se = wredf(ex);
      const float pp = ex / se;
      const float ht = wredf(-pp * logf(pp + 1e-12f));
      if (tid == 0) sh_fmisc[0] = fminf(1.0f, ht / logf(64.0f));
    }
    __syncthreads();
    const float gain = sh_fmisc[0];
    int kdi = (int)(2048.0f * (0.05f + 0.25f * gain));
    kdi = kdi < 1 ? 1 : (kdi > NN ? NN : kdi);
    // dynamic top-k on x (L0 prebuilt via exchange; levels 1-3 plain, reused)
    const unsigned xm = select_exch(xkeys, kdi, tid, sh_h2x,
                                    sh_hl1, sh_hl2, sh_hl3, sh_cw);
    // zero plain level buffers for next step's y-select
    sh_hl1[tid] = 0u; sh_hl2[tid] = 0u; sh_hl3[tid] = 0u;
    #pragma unroll
    for (int j = 0; j < 8; ++j) {
      const int g = 8*tid + j;
      const unsigned l = (unsigned)(g - n0);
      if (l < (unsigned)CH) {
        const float xv = __uint_as_float(xkeys[j]);
        const float v = ((xm >> j) & 1u) ? xv : 0.0f;
        sh_xstate[l] = v;
        sh_ffac[l] = (v <= 0.0f) ? (1.0f - 0.01f) : 1.0f;
      }
    }
    __syncthreads();
    {
      const float vd = sh_v[par][d4];
      float* rr = &sh_rho[d4][0];
      #pragma unroll
      for (int j = 0; j < 32; ++j) {
        const int c = p4 + 4*j;
        rr[c] = 0.97f * (rr[c]*sh_ffac[c] + gain * (vd * sh_xstate[c]));
      }
    }
    __syncthreads();   // protect sh_v/sh_xstate/rho before next iteration
  }
}

extern "C" void kernel_launch(void* const* d_in, const int* in_sizes, int n_in,
                              void* d_out, int out_size, void* d_ws, size_t ws_size,
                              hipStream_t stream) {
  const int*   tokens = (const int*)d_in[0];
  const float* spike  = (const float*)d_in[1];
  const float* Emat   = (const float*)d_in[2];
  const float* Dx     = (const float*)d_in[3];
  const float* Dy     = (const float*)d_in[4];
  const float* temb   = (const float*)d_in[5];
  float* out = (float*)d_out;
  (void)in_sizes; (void)n_in; (void)out_size; (void)d_ws; (void)ws_size;
  bdh_init<<<dim3(64), dim3(NTH), 0, stream>>>(Emat);
  bdh_main<<<dim3(NB), dim3(NTH), 0, stream>>>(tokens, spike, Emat, Dx, Dy, temb, out);
}